// Round 8
// baseline (537.174 us; speedup 1.0000x reference)
//
#include <hip/hip_runtime.h>
#include <math.h>

// CapsuleLayer dynamic routing, fp32, MI355X (gfx950).
// B=64, IN_CAPS=2048, IN_DIM=8, OUT_CAPS=32, OUT_DIM=16, 3 routing iters.
//
// b_ij after r updates = u_hat_i . (v0+...+v_{r-1}) (b starts at 0), so no
// u_hat materialization: each pass recomputes u_hat from W via LDS staging.
//
// R9 -> R10: R9's hipLaunchCooperativeKernel is NOT graph-capturable -> the
// kernel never ran (output all zeros; absmax 4.8e-2 == full |v| magnitude).
// R10 keeps the same fused structure but replaces grid.sync() with a
// HAND-ROLLED generation barrier on device-scope atomics:
//   release side: agent-scope ACQ_REL fetch_add on cnt (emits buffer_wbl2 ->
//   XCD L2 writeback); last arriver resets cnt, RELEASE-bumps gen;
//   acquire side: ACQUIRE spin on gen (emits buffer_inv -> XCD L2 inval).
// This is the documented cross-XCD visibility protocol (Guideline 16) and
// exactly what cooperative groups does internally. Co-residency of all 512
// blocks is guaranteed by construction: (256,2) launch bounds (R6 compiled
// to 172 VGPR -> no cap pressure, no spill) + 41KB LDS -> exactly 2
// blocks/CU x 256 CU. Barrier state (8B) sits in d_ws past part+vsum and is
// zeroed by a graph-capturable hipMemsetAsync every replay (re-poison safe).
// Fusion removes 5 kernel boundaries (~8us each: teardown+launch+ramp) and
// re-stages x/W prologues once per round instead of once per kernel.
// Compute body is R6's proven pass (XOR-swizzled conflict-free W reads,
// DPP softmax, double-buffered gll16 staging) - unchanged.

#define IC 2048
#define ID 8
#define OC 32
#define OD 16
#define B_N 64
#define S_ELEMS (B_N * OC * OD)   // 32768
#define IB 16                     // i's per block
#define ISTR (IC / IB)            // 128 i-stripes
#define BPB 16                    // b's per block (4 per wave)
#define BG (B_N / BPB)            // 4 b-groups
#define NBLK (BG * ISTR)          // 512 blocks = exactly 2/CU x 256 CU

// async 16B global->LDS (direct, no VGPR round trip)
__device__ __forceinline__ void gll16(const float4* g, float4* l)
{
    __builtin_amdgcn_global_load_lds(
        (const __attribute__((address_space(1))) void*)g,
        (__attribute__((address_space(3))) void*)l,
        16, 0, 0);
}

// x + dpp_perm(x) on the VALU pipe (no LDS traffic)
template <int CTRL>
__device__ __forceinline__ float dpp_add(float x)
{
    union { float f; int i; } a, b;
    a.f = x;
    b.i = __builtin_amdgcn_update_dpp(0, a.i, CTRL, 0xF, 0xF, true);
    return x + b.f;
}

// Generation barrier across all NBLK co-resident blocks (device scope).
__device__ __forceinline__ void gridbar(unsigned* cnt, unsigned* gen)
{
    __syncthreads();   // all waves of this block done with pre-barrier work
    if (threadIdx.x == 0) {
        const unsigned g =
            __hip_atomic_load(gen, __ATOMIC_RELAXED, __HIP_MEMORY_SCOPE_AGENT);
        const unsigned a =
            __hip_atomic_fetch_add(cnt, 1u, __ATOMIC_ACQ_REL,
                                   __HIP_MEMORY_SCOPE_AGENT);
        if (a == NBLK - 1) {
            // reset BEFORE release so next barrier's arrivals land on 0
            __hip_atomic_store(cnt, 0u, __ATOMIC_RELAXED,
                               __HIP_MEMORY_SCOPE_AGENT);
            __hip_atomic_fetch_add(gen, 1u, __ATOMIC_RELEASE,
                                   __HIP_MEMORY_SCOPE_AGENT);
        } else {
            while (__hip_atomic_load(gen, __ATOMIC_ACQUIRE,
                                     __HIP_MEMORY_SCOPE_AGENT) == g)
                __builtin_amdgcn_s_sleep(2);
        }
    }
    __syncthreads();   // all waves wait for thread 0's acquire
}

// W tile i is 1024 float4 "chunks"; global chunk f = (o*16 + j)*2 + dq.
// LDS layout: row o (32 chunks), chunk slot = (j*2+dq) ^ o.  Staging dest is
// linear D = s*256+tid; the matching pre-swizzled source is
//   f(D) = (D>>5)*32 + ((D&31) ^ (D>>5)).
// Hot read, fixed (jj,dq): lanes (o,jh) hit slot ((jh*16+jj*2+dq)^o) in row o
// -> slot%8 uniform over lanes -> conflict-free b128.

__launch_bounds__(256, 2)
__global__ void caps_fused(const float* __restrict__ Wg,
                           const float* __restrict__ xg,
                           float* __restrict__ part,
                           float* __restrict__ vsum,
                           float* __restrict__ out,
                           unsigned* __restrict__ bar)
{
    __shared__ float4 Wl[2][1024];      // 32 KB, double-buffered W tile
    __shared__ float4 xs[BPB * 2 * IB]; // 8 KB: x[b][i][h], all 16 i's
    __shared__ float red[4][64];        // 1 KB reduce scratch

    unsigned* cnt = bar;
    unsigned* gen = bar + 1;

    const int tid  = threadIdx.x;
    const int lane = tid & 63;
    const int w    = tid >> 6;        // wave 0..3
    const int o    = lane & 31;
    const int jh   = lane >> 5;

    const int is   = blockIdx.x & (ISTR - 1);  // same-W blocks are 128 apart
    const int bg   = blockIdx.x >> 7;          // -> land on the same XCD
    const int bblk = bg * BPB;
    const int ig0  = is * IB;
    const int e0   = blockIdx.x * 64;          // reduce element base

    const float4* wq = (const float4*)Wg;
    const float4* xq = (const float4*)xg;

    // ---- x for all 16 i's of this (b-group, i-stripe): loaded ONCE.
    // xs slot s = b*32 + i*2 + h  <-  xq[((bblk+b)*IC + ig0)*2 + i*2+h]
#pragma unroll
    for (int q = 0; q < 2; ++q) {
        const int s = q * 256 + tid;
        const int b = s >> 5;
        const int rr = s & 31;
        gll16(xq + ((size_t)(bblk + b) * IC + ig0) * 2 + rr, &xs[s]);
    }

    // stage W tile t into parity buffer (4 gll16 per thread)
    auto stage = [&](int t, int parity) {
        const size_t wb0 = (size_t)(ig0 + t) * 1024;
        float4* dst = Wl[parity];
#pragma unroll
        for (int s4 = 0; s4 < 4; ++s4) {
            const int D = s4 * 256 + tid;
            const int orow = D >> 5;
            const int f = orow * 32 + ((D & 31) ^ orow);
            gll16(wq + wb0 + f, dst + D);
        }
    };

    for (int r = 0; r < 3; ++r) {
        // v-sum fragments for this wave's 4 b's (rounds 1,2)
        float4 va[4], vb[4];
        if (r) {
#pragma unroll
            for (int n = 0; n < 4; ++n) {
                const float* vp = vsum + (size_t)(bblk + w * 4 + n) * (OC * OD)
                                + o * OD + jh * 8;
                va[n] = ((const float4*)vp)[0];
                vb[n] = ((const float4*)vp)[1];
            }
        }

        float acc[4][8];
#pragma unroll
        for (int n = 0; n < 4; ++n)
#pragma unroll
            for (int jj = 0; jj < 8; ++jj) acc[n][jj] = 0.0f;

        stage(0, 0);   // prologue tile of this round

        for (int il = 0; il < IB; ++il) {
            const int p = il & 1;
            __syncthreads();   // tile il (and round-0: x) landed; p^1 free

            if (il + 1 < IB) stage(il + 1, p ^ 1);

            // W fragment -> registers (16 conflict-free ds_read_b128)
            float4 wA[8], wB[8];
            const int row = o * 32;
#pragma unroll
            for (int jj = 0; jj < 8; ++jj) {
                const int ca = (jh * 16 + jj * 2) ^ o;   // dq=0 slot
                wA[jj] = Wl[p][row + ca];
                wB[jj] = Wl[p][row + (ca ^ 1)];          // dq=1 slot
            }

#pragma unroll
            for (int n = 0; n < 4; ++n) {
                const float4 xa = xs[(w * 4 + n) * 32 + il * 2];
                const float4 xb = xs[(w * 4 + n) * 32 + il * 2 + 1];
                float u[8];
#pragma unroll
                for (int jj = 0; jj < 8; ++jj) {
                    float t = wA[jj].x * xa.x;
                    t = fmaf(wA[jj].y, xa.y, t);
                    t = fmaf(wA[jj].z, xa.z, t);
                    t = fmaf(wA[jj].w, xa.w, t);
                    t = fmaf(wB[jj].x, xb.x, t);
                    t = fmaf(wB[jj].y, xb.y, t);
                    t = fmaf(wB[jj].z, xb.z, t);
                    t = fmaf(wB[jj].w, xb.w, t);
                    u[jj] = t;
                }
                float cc;
                if (r == 0) {
                    cc = 1.0f;  // softmax(0) = 1/32, folded into store scale
                } else {
                    float bp = u[0] * va[n].x;
                    bp = fmaf(u[1], va[n].y, bp);
                    bp = fmaf(u[2], va[n].z, bp);
                    bp = fmaf(u[3], va[n].w, bp);
                    bp = fmaf(u[4], vb[n].x, bp);
                    bp = fmaf(u[5], vb[n].y, bp);
                    bp = fmaf(u[6], vb[n].z, bp);
                    bp = fmaf(u[7], vb[n].w, bp);
                    bp += __shfl_xor(bp, 32);            // combine j-halves
                    // no max-subtraction: |logit| tiny, exp safe in fp32
                    const float e = __expf(bp);
                    float t = dpp_add<0xB1>(e);          // quad_perm xor1
                    t = dpp_add<0x4E>(t);                // quad_perm xor2
                    t = dpp_add<0x124>(t);               // row_ror:4
                    t = dpp_add<0x128>(t);               // row_ror:8 -> rowsum
                    const float se = t + __shfl_xor(t, 16);  // 32-o total
                    cc = e * __builtin_amdgcn_rcpf(se);
                }
#pragma unroll
                for (int jj = 0; jj < 8; ++jj)
                    acc[n][jj] = fmaf(cc, u[jj], acc[n][jj]);
            }
        }

        // disjoint per-(istripe, b) partials — no atomics, no memset needed
        const float scale = (r == 0) ? (1.0f / 32.0f) : 1.0f;
#pragma unroll
        for (int n = 0; n < 4; ++n) {
            float* dst = part + (size_t)is * S_ELEMS
                       + (size_t)(bblk + w * 4 + n) * (OC * OD) + o * OD + jh * 8;
            float4 lo = {acc[n][0] * scale, acc[n][1] * scale,
                         acc[n][2] * scale, acc[n][3] * scale};
            float4 hi = {acc[n][4] * scale, acc[n][5] * scale,
                         acc[n][6] * scale, acc[n][7] * scale};
            ((float4*)dst)[0] = lo;
            ((float4*)dst)[1] = hi;
        }

        gridbar(cnt, gen);   // partials visible device-wide

        // ---- inline 128-way partial reduction + squash (64 elems/block).
        // Wave w sums stripes k===w (mod 4), coalesced 256B wave-loads.
        float s = 0.0f;
#pragma unroll 8
        for (int k = w; k < ISTR; k += 4)
            s += part[(size_t)k * S_ELEMS + e0 + lane];
        red[w][lane] = s;
        __syncthreads();

        if (tid < 64) {
            const float t = red[0][tid] + red[1][tid] + red[2][tid] + red[3][tid];
            float s2 = t * t;               // ||s||^2 over the 16 j's
            s2 += __shfl_xor(s2, 1);
            s2 += __shfl_xor(s2, 2);
            s2 += __shfl_xor(s2, 4);
            s2 += __shfl_xor(s2, 8);
            const float v = t * (s2 / ((1.0f + s2) * sqrtf(s2 + 1e-9f)));
            const int e = e0 + tid;
            if (r == 0)      vsum[e] = v;   // vsum = v0
            else if (r == 1) vsum[e] += v;  // vsum = v0+v1
            else             out[e] = v;    // out = v2
        }

        if (r < 2)
            gridbar(cnt, gen);  // vsum visible; part safe to overwrite
    }
}

extern "C" void kernel_launch(void* const* d_in, const int* in_sizes, int n_in,
                              void* d_out, int out_size, void* d_ws, size_t ws_size,
                              hipStream_t stream)
{
    const float* x = (const float*)d_in[0];   // [64, 2048, 8]
    const float* W = (const float*)d_in[1];   // [1, 2048, 32, 16, 8]
    float* out = (float*)d_out;               // [64, 32, 16]

    float* part = (float*)d_ws;                        // 128 x 32768 = 16.8 MB
    float* vsum = part + (size_t)ISTR * S_ELEMS;       // 32768 floats
    unsigned* bar = (unsigned*)(vsum + S_ELEMS);       // 2 x u32 barrier state

    // zero barrier state every graph replay (workspace may be re-poisoned)
    hipMemsetAsync(bar, 0, 2 * sizeof(unsigned), stream);

    caps_fused<<<dim3(NBLK), dim3(256), 0, stream>>>(W, x, part, vsum, out,
                                                     bar);
}

// Round 9
// 183.310 us; speedup vs baseline: 2.9304x; 2.9304x over previous
//
#include <hip/hip_runtime.h>
#include <math.h>

// CapsuleLayer dynamic routing, fp32, MI355X (gfx950).
// B=64, IN_CAPS=2048, IN_DIM=8, OUT_CAPS=32, OUT_DIM=16, 3 routing iters.
//
// b_ij after r updates = u_hat_i . (v0+...+v_{r-1}) (b starts at 0), so no
// u_hat materialization: each pass recomputes u_hat from W via LDS staging.
//
// R10 -> R11: fusion reverted (spilled to 128 VGPR -> 477us steady; grid
// barrier fragile under profiling: 40ms preemption outlier). Base is R6
// (169.8us = fill ~43 + 3x pass ~36 + reduces ~12 + gaps). Pass runs at
// ~35% of both VALU and LDS pipes with 2 waves/SIMD -> dep-latency-bound
// between barriers. R8 showed waitcnt style is not the lever; R11 tests
// BARRIER FREQUENCY: quad-buffered W (64KB), stage 2 tiles + compute 2
// tiles per __syncthreads -> 8 barriers/pass (was 16) and a 2x-wide
// independent instruction window per phase. x preloaded once to LDS (8KB,
// R8's idea; race-free here since __syncthreads drains vmcnt(0)); W read
// indices force-hoisted to registers. LDS 72.3KB -> still 2 blocks/CU.
// Barrier drains exactly the 2 tiles needed (prefetch issued after it).

#define IC 2048
#define ID 8
#define OC 32
#define OD 16
#define B_N 64
#define S_ELEMS (B_N * OC * OD)   // 32768
#define IB 16                     // i's per block
#define ISTR (IC / IB)            // 128 i-stripes
#define BPB 16                    // b's per block (4 per wave)
#define BG (B_N / BPB)            // 4 b-groups

// async 16B global->LDS (direct, no VGPR round trip)
__device__ __forceinline__ void gll16(const float4* g, float4* l)
{
    __builtin_amdgcn_global_load_lds(
        (const __attribute__((address_space(1))) void*)g,
        (__attribute__((address_space(3))) void*)l,
        16, 0, 0);
}

// x + dpp_perm(x) on the VALU pipe (no LDS traffic)
template <int CTRL>
__device__ __forceinline__ float dpp_add(float x)
{
    union { float f; int i; } a, b;
    a.f = x;
    b.i = __builtin_amdgcn_update_dpp(0, a.i, CTRL, 0xF, 0xF, true);
    return x + b.f;
}

// W tile i is 1024 float4 "chunks"; global chunk f = (o*16 + j)*2 + dq.
// LDS layout: row o (32 chunks), chunk slot = (j*2+dq) ^ o.  Staging dest is
// linear D = s*256+tid; the matching pre-swizzled source is
//   f(D) = (D>>5)*32 + ((D&31) ^ (D>>5)).
// Hot read, fixed (jj,dq): lanes (o,jh) hit slot ((jh*16+jj*2+dq)^o) in row o
// -> slot%8 uniform over lanes -> conflict-free b128.

template <int FIRST>
__launch_bounds__(256, 2)
__global__ void caps_pass(const float* __restrict__ Wg,
                          const float* __restrict__ xg,
                          const float* __restrict__ vs,
                          float* __restrict__ part)
{
    __shared__ float4 Wl[4][1024];      // 64 KB, quad-buffered W tiles
    __shared__ float4 xs[BPB * 2 * IB]; // 8 KB: x[b][i][h], all 16 i's

    const int tid  = threadIdx.x;
    const int lane = tid & 63;
    const int w    = tid >> 6;        // wave 0..3
    const int o    = lane & 31;
    const int jh   = lane >> 5;

    const int is   = blockIdx.x & (ISTR - 1);  // same-W blocks are 128 apart
    const int bg   = blockIdx.x >> 7;          // -> land on the same XCD
    const int bblk = bg * BPB;
    const int ig0  = is * IB;

    const float4* wq = (const float4*)Wg;
    const float4* xq = (const float4*)xg;

    // v-sum fragments for this wave's 4 b's, held across the i-loop
    float4 va[4], vb[4];
    if (!FIRST) {
#pragma unroll
        for (int n = 0; n < 4; ++n) {
            const float* vp =
                vs + (size_t)(bblk + w * 4 + n) * (OC * OD) + o * OD + jh * 8;
            va[n] = ((const float4*)vp)[0];
            vb[n] = ((const float4*)vp)[1];
        }
    }

    float acc[4][8];
#pragma unroll
    for (int n = 0; n < 4; ++n)
#pragma unroll
        for (int jj = 0; jj < 8; ++jj) acc[n][jj] = 0.0f;

    // loop-invariant swizzled W read indices, pinned in registers
    int caA[8];
#pragma unroll
    for (int jj = 0; jj < 8; ++jj) caA[jj] = (o << 5) + ((jh * 16 + jj * 2) ^ o);

    // stage W tile t into Wl[t&3] (4 gll16 per thread)
    auto stage = [&](int t) {
        const size_t wb0 = (size_t)(ig0 + t) * 1024;
        float4* dst = Wl[t & 3];
#pragma unroll
        for (int s4 = 0; s4 < 4; ++s4) {
            const int D = s4 * 256 + tid;
            const int orow = D >> 5;
            const int f = orow * 32 + ((D & 31) ^ orow);
            gll16(wq + wb0 + f, dst + D);
        }
    };

    // ---- prologue: x (all 16 i's) + W tiles 0,1
    {
#pragma unroll
        for (int q = 0; q < 2; ++q) {
            const int s = q * 256 + tid;
            const int b = s >> 5;
            const int rr = s & 31;
            gll16(xq + ((size_t)(bblk + b) * IC + ig0) * 2 + rr, &xs[s]);
        }
        stage(0);
        stage(1);
    }

    // compute one i-tile from Wl[il&3]
    auto compute = [&](int il) {
        float4 wA[8], wB[8];
        const float4* buf = Wl[il & 3];
#pragma unroll
        for (int jj = 0; jj < 8; ++jj) {
            wA[jj] = buf[caA[jj]];
            wB[jj] = buf[caA[jj] ^ 1];
        }

#pragma unroll
        for (int n = 0; n < 4; ++n) {
            const float4 xa = xs[(w * 4 + n) * 32 + il * 2];
            const float4 xb = xs[(w * 4 + n) * 32 + il * 2 + 1];
            float u[8];
#pragma unroll
            for (int jj = 0; jj < 8; ++jj) {
                float t = wA[jj].x * xa.x;
                t = fmaf(wA[jj].y, xa.y, t);
                t = fmaf(wA[jj].z, xa.z, t);
                t = fmaf(wA[jj].w, xa.w, t);
                t = fmaf(wB[jj].x, xb.x, t);
                t = fmaf(wB[jj].y, xb.y, t);
                t = fmaf(wB[jj].z, xb.z, t);
                t = fmaf(wB[jj].w, xb.w, t);
                u[jj] = t;
            }
            float cc;
            if (FIRST) {
                cc = 1.0f;  // softmax(0) = 1/32, folded into the store scale
            } else {
                float bp = u[0] * va[n].x;
                bp = fmaf(u[1], va[n].y, bp);
                bp = fmaf(u[2], va[n].z, bp);
                bp = fmaf(u[3], va[n].w, bp);
                bp = fmaf(u[4], vb[n].x, bp);
                bp = fmaf(u[5], vb[n].y, bp);
                bp = fmaf(u[6], vb[n].z, bp);
                bp = fmaf(u[7], vb[n].w, bp);
                bp += __shfl_xor(bp, 32);            // combine j-halves
                // no max-subtraction: |logit| tiny, exp safe in fp32
                const float e = __expf(bp);
                float t = dpp_add<0xB1>(e);          // quad_perm xor1
                t = dpp_add<0x4E>(t);                // quad_perm xor2
                t = dpp_add<0x124>(t);               // row_ror:4
                t = dpp_add<0x128>(t);               // row_ror:8 -> row sum
                const float se = t + __shfl_xor(t, 16);  // 32-o total
                cc = e * __builtin_amdgcn_rcpf(se);
            }
#pragma unroll
            for (int jj = 0; jj < 8; ++jj)
                acc[n][jj] = fmaf(cc, u[jj], acc[n][jj]);
        }
    };

    // ---- main loop: 8 phases, 2 i-tiles per barrier.
    // Barrier at phase top drains the 2 stages issued last phase (exactly
    // the tiles consumed now); this phase's prefetch is issued after it.
    for (int ph = 0; ph < IB / 2; ++ph) {
        const int il = ph * 2;
        __syncthreads();
        if (il + 2 < IB) {
            stage(il + 2);
            stage(il + 3);
        }
        compute(il);
        compute(il + 1);
    }

    // disjoint per-(istripe, b) partials — no atomics, no memset needed
    const float scale = FIRST ? (1.0f / 32.0f) : 1.0f;
#pragma unroll
    for (int n = 0; n < 4; ++n) {
        float* dst = part + (size_t)is * S_ELEMS
                   + (size_t)(bblk + w * 4 + n) * (OC * OD) + o * OD + jh * 8;
        float4 lo = {acc[n][0] * scale, acc[n][1] * scale,
                     acc[n][2] * scale, acc[n][3] * scale};
        float4 hi = {acc[n][4] * scale, acc[n][5] * scale,
                     acc[n][6] * scale, acc[n][7] * scale};
        ((float4*)dst)[0] = lo;
        ((float4*)dst)[1] = hi;
    }
}

// Fused 128-way partial reduction + squash, 512 blocks (2/CU).
// Block handles 64 elems; wave w sums stripes k===w (mod 4), coalesced 256B
// wave-loads; 4-way LDS combine; squash over 16-j lane groups.
// MODE 0: vsum = v   MODE 1: vsum += v   MODE 2: out = v
template <int MODE>
__launch_bounds__(256, 4)
__global__ void caps_reduce(const float* __restrict__ part,
                            float* __restrict__ vsum,
                            float* __restrict__ out)
{
    __shared__ float red[4][64];
    const int tid  = threadIdx.x;
    const int w    = tid >> 6;
    const int lane = tid & 63;
    const int e0   = blockIdx.x * 64;

    float s = 0.0f;
#pragma unroll 8
    for (int k = w; k < ISTR; k += 4)
        s += part[(size_t)k * S_ELEMS + e0 + lane];
    red[w][lane] = s;
    __syncthreads();

    if (tid < 64) {
        const float t = red[0][tid] + red[1][tid] + red[2][tid] + red[3][tid];
        float s2 = t * t;               // ||s||^2 over the 16 j's
        s2 += __shfl_xor(s2, 1);
        s2 += __shfl_xor(s2, 2);
        s2 += __shfl_xor(s2, 4);
        s2 += __shfl_xor(s2, 8);
        const float v = t * (s2 / ((1.0f + s2) * sqrtf(s2 + 1e-9f)));
        const int e = e0 + tid;
        if (MODE == 0)      vsum[e] = v;
        else if (MODE == 1) vsum[e] += v;
        else                out[e] = v;
    }
}

extern "C" void kernel_launch(void* const* d_in, const int* in_sizes, int n_in,
                              void* d_out, int out_size, void* d_ws, size_t ws_size,
                              hipStream_t stream)
{
    const float* x = (const float*)d_in[0];   // [64, 2048, 8]
    const float* W = (const float*)d_in[1];   // [1, 2048, 32, 16, 8]
    float* out = (float*)d_out;               // [64, 32, 16]

    float* part = (float*)d_ws;                        // 128 x 32768 = 16.8 MB
    float* vsum = part + (size_t)ISTR * S_ELEMS;       // 32768 floats

    const dim3 gP(BG * ISTR);     // 512 blocks = 2/CU
    const dim3 bP(256);
    const dim3 gR(S_ELEMS / 64);  // 512 blocks
    const dim3 bR(256);

    // round 0: c uniform
    caps_pass<1><<<gP, bP, 0, stream>>>(W, x, nullptr, part);
    caps_reduce<0><<<gR, bR, 0, stream>>>(part, vsum, out);   // vsum = v0
    // round 1: b = u.v0
    caps_pass<0><<<gP, bP, 0, stream>>>(W, x, vsum, part);
    caps_reduce<1><<<gR, bR, 0, stream>>>(part, vsum, out);   // vsum = v0+v1
    // round 2: b = u.(v0+v1)
    caps_pass<0><<<gP, bP, 0, stream>>>(W, x, vsum, part);
    caps_reduce<2><<<gR, bR, 0, stream>>>(part, vsum, out);   // out = v2
}

// Round 10
// 167.070 us; speedup vs baseline: 3.2153x; 1.0972x over previous
//
#include <hip/hip_runtime.h>
#include <hip/hip_fp16.h>
#include <math.h>

// CapsuleLayer dynamic routing, fp32, MI355X (gfx950).
// B=64, IN_CAPS=2048, IN_DIM=8, OUT_CAPS=32, OUT_DIM=16, 3 routing iters.
//
// b_ij after r updates = u_hat_i . (v0+...+v_{r-1}) (b starts at 0), so no
// u_hat materialization: each pass recomputes u_hat from W via LDS staging.
//
// R11 -> R12: R11's restructure flipped the allocator into spill mode again
// (VGPR 128, WRITE +8MB scratch) -- 3rd confirmation of the ~170-VGPR
// regalloc cliff. Base reverts to R6 (169.8us, 172 VGPR). R12 aims for a
// THIRD resident block/CU WITHOUT launch-bounds pressure (R4/R7 lesson):
//  - one-shot x preload to LDS (R8-proven VGPR-safe): frees the per-iter
//    gx float4 + flag + address regs (~6) from the loop;
//  - fp16 partials: epilogue-only; precision bound ~3e-5 << 9.6e-4 thresh
//    (partial std ~3.5e-3, fp16 rel eps 4.9e-4, sqrt(256) accumulation);
//  - IB=8 -> 1024 blocks (4 dispatched/CU) so 3 can be resident if the
//    natural allocation lands <=170 (3 waves/SIMD x 170 = 510 <= 512);
//    LDS 32KB W + 4KB x = 36KB -> 3x108KB <= 160KB. fp16 keeps the doubled
//    stripe count at R6's byte volume (256 x 32768 x 2B = 16.8MB).
// Hedge: if VGPR lands 171+ (no spill) -> 2 resident blocks, ~neutral vs
// R6 and we learn the exact allocation; WRITE >> 17MB/pass = spill = revert.
// Compute body is R6's proven pass (XOR-swizzled conflict-free W reads,
// DPP softmax, double-buffered gll16 staging) -- unchanged.

#define IC 2048
#define ID 8
#define OC 32
#define OD 16
#define B_N 64
#define S_ELEMS (B_N * OC * OD)   // 32768
#define IB 8                      // i's per block
#define ISTR (IC / IB)            // 256 i-stripes
#define BPB 16                    // b's per block (4 per wave)
#define BG (B_N / BPB)            // 4 b-groups

// async 16B global->LDS (direct, no VGPR round trip)
__device__ __forceinline__ void gll16(const float4* g, float4* l)
{
    __builtin_amdgcn_global_load_lds(
        (const __attribute__((address_space(1))) void*)g,
        (__attribute__((address_space(3))) void*)l,
        16, 0, 0);
}

// x + dpp_perm(x) on the VALU pipe (no LDS traffic)
template <int CTRL>
__device__ __forceinline__ float dpp_add(float x)
{
    union { float f; int i; } a, b;
    a.f = x;
    b.i = __builtin_amdgcn_update_dpp(0, a.i, CTRL, 0xF, 0xF, true);
    return x + b.f;
}

// W tile i is 1024 float4 "chunks"; global chunk f = (o*16 + j)*2 + dq.
// LDS layout: row o (32 chunks), chunk slot = (j*2+dq) ^ o.  Staging dest is
// linear D = s*256+tid; the matching pre-swizzled source is
//   f(D) = (D>>5)*32 + ((D&31) ^ (D>>5)).
// Hot read, fixed (jj,dq): lanes (o,jh) hit slot ((jh*16+jj*2+dq)^o) in row o
// -> slot%8 uniform over lanes -> conflict-free b128.

template <int FIRST>
__launch_bounds__(256, 2)
__global__ void caps_pass(const float* __restrict__ Wg,
                          const float* __restrict__ xg,
                          const float* __restrict__ vs,
                          __half* __restrict__ part)
{
    __shared__ float4 Wl[2][1024];      // 32 KB, double-buffered W tile
    __shared__ float4 xs[BPB * 2 * IB]; // 4 KB: x[b][i][h], all 8 i's

    const int tid  = threadIdx.x;
    const int lane = tid & 63;
    const int w    = tid >> 6;        // wave 0..3
    const int o    = lane & 31;
    const int jh   = lane >> 5;

    const int is   = blockIdx.x & (ISTR - 1);  // same-W blocks are 256 apart
    const int bg   = blockIdx.x >> 8;          // -> land on the same XCD
    const int bblk = bg * BPB;
    const int ig0  = is * IB;

    const float4* wq = (const float4*)Wg;
    const float4* xq = (const float4*)xg;

    // v-sum fragments for this wave's 4 b's, held across the i-loop
    float4 va[4], vb[4];
    if (!FIRST) {
#pragma unroll
        for (int n = 0; n < 4; ++n) {
            const float* vp =
                vs + (size_t)(bblk + w * 4 + n) * (OC * OD) + o * OD + jh * 8;
            va[n] = ((const float4*)vp)[0];
            vb[n] = ((const float4*)vp)[1];
        }
    }

    float acc[4][8];
#pragma unroll
    for (int n = 0; n < 4; ++n)
#pragma unroll
        for (int jj = 0; jj < 8; ++jj) acc[n][jj] = 0.0f;

    // stage W tile t into parity buffer (4 gll16 per thread)
    auto stage = [&](int t, int parity) {
        const size_t wb0 = (size_t)(ig0 + t) * 1024;
        float4* dst = Wl[parity];
#pragma unroll
        for (int s4 = 0; s4 < 4; ++s4) {
            const int D = s4 * 256 + tid;
            const int orow = D >> 5;
            const int f = orow * 32 + ((D & 31) ^ orow);
            gll16(wq + wb0 + f, dst + D);
        }
    };

    // ---- prologue: W tile 0 + ALL x for this (b-group, i-stripe).
    // xs slot s = b*16 + i*2 + h  <-  xq[((bblk+b)*IC + ig0)*2 + i*2+h]
    stage(0, 0);
    {
        const int b  = tid >> 4;
        const int rr = tid & 15;
        gll16(xq + ((size_t)(bblk + b) * IC + ig0) * 2 + rr, &xs[tid]);
    }

    for (int il = 0; il < IB; ++il) {
        const int p = il & 1;
        __syncthreads();   // tile il (and il=0: x) landed; parity p^1 free

        if (il + 1 < IB) stage(il + 1, p ^ 1);

        // W fragment -> registers (16 conflict-free ds_read_b128)
        float4 wA[8], wB[8];
        const int row = o * 32;
#pragma unroll
        for (int jj = 0; jj < 8; ++jj) {
            const int ca = (jh * 16 + jj * 2) ^ o;   // dq=0 slot
            wA[jj] = Wl[p][row + ca];
            wB[jj] = Wl[p][row + (ca ^ 1)];          // dq=1 slot
        }

#pragma unroll
        for (int n = 0; n < 4; ++n) {
            const float4 xa = xs[(w * 4 + n) * 16 + il * 2];
            const float4 xb = xs[(w * 4 + n) * 16 + il * 2 + 1];
            float u[8];
#pragma unroll
            for (int jj = 0; jj < 8; ++jj) {
                float t = wA[jj].x * xa.x;
                t = fmaf(wA[jj].y, xa.y, t);
                t = fmaf(wA[jj].z, xa.z, t);
                t = fmaf(wA[jj].w, xa.w, t);
                t = fmaf(wB[jj].x, xb.x, t);
                t = fmaf(wB[jj].y, xb.y, t);
                t = fmaf(wB[jj].z, xb.z, t);
                t = fmaf(wB[jj].w, xb.w, t);
                u[jj] = t;
            }
            float cc;
            if (FIRST) {
                cc = 1.0f;  // softmax(0) = 1/32, folded into the store scale
            } else {
                float bp = u[0] * va[n].x;
                bp = fmaf(u[1], va[n].y, bp);
                bp = fmaf(u[2], va[n].z, bp);
                bp = fmaf(u[3], va[n].w, bp);
                bp = fmaf(u[4], vb[n].x, bp);
                bp = fmaf(u[5], vb[n].y, bp);
                bp = fmaf(u[6], vb[n].z, bp);
                bp = fmaf(u[7], vb[n].w, bp);
                bp += __shfl_xor(bp, 32);            // combine j-halves
                // no max-subtraction: |logit| tiny, exp safe in fp32
                const float e = __expf(bp);
                float t = dpp_add<0xB1>(e);          // quad_perm xor1
                t = dpp_add<0x4E>(t);                // quad_perm xor2
                t = dpp_add<0x124>(t);               // row_ror:4
                t = dpp_add<0x128>(t);               // row_ror:8 -> row sum
                const float se = t + __shfl_xor(t, 16);  // 32-o total
                cc = e * __builtin_amdgcn_rcpf(se);
            }
#pragma unroll
            for (int jj = 0; jj < 8; ++jj)
                acc[n][jj] = fmaf(cc, u[jj], acc[n][jj]);
        }
    }

    // disjoint per-(istripe, b) fp16 partials — no atomics, no memset needed
    const float scale = FIRST ? (1.0f / 32.0f) : 1.0f;
#pragma unroll
    for (int n = 0; n < 4; ++n) {
        __half* dst = part + (size_t)is * S_ELEMS
                    + (size_t)(bblk + w * 4 + n) * (OC * OD) + o * OD + jh * 8;
        union { __half h[8]; uint4 u4; } pk;
#pragma unroll
        for (int jj = 0; jj < 8; ++jj)
            pk.h[jj] = __float2half(acc[n][jj] * scale);
        *(uint4*)dst = pk.u4;   // 16B-aligned: (o*16 + jh*8)*2 bytes
    }
}

// Fused 256-way fp16-partial reduction + squash, 512 blocks (2/CU).
// Block handles 64 elems; wave w sums stripes k===w (mod 4), coalesced 128B
// wave-loads; 4-way LDS combine; squash over 16-j lane groups.
// MODE 0: vsum = v   MODE 1: vsum += v   MODE 2: out = v
template <int MODE>
__launch_bounds__(256, 4)
__global__ void caps_reduce(const __half* __restrict__ part,
                            float* __restrict__ vsum,
                            float* __restrict__ out)
{
    __shared__ float red[4][64];
    const int tid  = threadIdx.x;
    const int w    = tid >> 6;
    const int lane = tid & 63;
    const int e0   = blockIdx.x * 64;

    float s = 0.0f;
#pragma unroll 8
    for (int k = w; k < ISTR; k += 4)
        s += __half2float(part[(size_t)k * S_ELEMS + e0 + lane]);
    red[w][lane] = s;
    __syncthreads();

    if (tid < 64) {
        const float t = red[0][tid] + red[1][tid] + red[2][tid] + red[3][tid];
        float s2 = t * t;               // ||s||^2 over the 16 j's
        s2 += __shfl_xor(s2, 1);
        s2 += __shfl_xor(s2, 2);
        s2 += __shfl_xor(s2, 4);
        s2 += __shfl_xor(s2, 8);
        const float v = t * (s2 / ((1.0f + s2) * sqrtf(s2 + 1e-9f)));
        const int e = e0 + tid;
        if (MODE == 0)      vsum[e] = v;
        else if (MODE == 1) vsum[e] += v;
        else                out[e] = v;
    }
}

extern "C" void kernel_launch(void* const* d_in, const int* in_sizes, int n_in,
                              void* d_out, int out_size, void* d_ws, size_t ws_size,
                              hipStream_t stream)
{
    const float* x = (const float*)d_in[0];   // [64, 2048, 8]
    const float* W = (const float*)d_in[1];   // [1, 2048, 32, 16, 8]
    float* out = (float*)d_out;               // [64, 32, 16]

    __half* part = (__half*)d_ws;             // 256 x 32768 x 2B = 16.8 MB
    float* vsum = (float*)((char*)d_ws + (size_t)ISTR * S_ELEMS * sizeof(__half));

    const dim3 gP(BG * ISTR);     // 1024 blocks (4 dispatched/CU)
    const dim3 bP(256);
    const dim3 gR(S_ELEMS / 64);  // 512 blocks
    const dim3 bR(256);

    // round 0: c uniform
    caps_pass<1><<<gP, bP, 0, stream>>>(W, x, nullptr, part);
    caps_reduce<0><<<gR, bR, 0, stream>>>(part, vsum, out);   // vsum = v0
    // round 1: b = u.v0
    caps_pass<0><<<gP, bP, 0, stream>>>(W, x, vsum, part);
    caps_reduce<1><<<gR, bR, 0, stream>>>(part, vsum, out);   // vsum = v0+v1
    // round 2: b = u.(v0+v1)
    caps_pass<0><<<gP, bP, 0, stream>>>(W, x, vsum, part);
    caps_reduce<2><<<gR, bR, 0, stream>>>(part, vsum, out);   // out = v2
}

// Round 11
// 166.802 us; speedup vs baseline: 3.2204x; 1.0016x over previous
//
#include <hip/hip_runtime.h>
#include <hip/hip_fp16.h>
#include <math.h>

// CapsuleLayer dynamic routing, fp32, MI355X (gfx950).
// B=64, IN_CAPS=2048, IN_DIM=8, OUT_CAPS=32, OUT_DIM=16, 3 routing iters.
//
// b_ij after r updates = u_hat_i . (v0+...+v_{r-1}) (b starts at 0), so no
// u_hat materialization: each pass recomputes u_hat from W via LDS staging.
//
// R12 -> R13: R12 (167.1us, VGPR 120, no spill) showed 2x potential
// residency moved NOTHING (VALUBusy 35->37%, pass 43.4us) -> not
// wave-supply-bound; per-CU pipe demand is the cost. The computable waste:
// W LDS reads are duplicated 4x across waves (each wave reads the full
// 16KB tile for only 4 b's) and W staging is duplicated across 4 b-groups.
// R13 amortizes W over 8 b's/wave (BPB=32, BG=2): GPU-wide W LDS reads and
// W staging HALVE; x broadcasts constant; VALU ~constant. This per-wave
// body (acc[8][8], va/vb[8], wA/wB[8]) compiled spill-free at 172 VGPR in
// R3 (R3's failure was the 128-thr block shape, not the body). Everything
// R12 proved stays: 256-thr blocks, (256,2) no-pressure bounds, gll16+XOR
// swizzle, one-shot x preload, DPP softmax, fp16 partials (margin 8x).
// Grid 512 = 2 blocks/CU; LDS 40KB. Tripwires: WRITE>17MB or FETCH>40MB
// per pass = spill -> revert to R12.

#define IC 2048
#define ID 8
#define OC 32
#define OD 16
#define B_N 64
#define S_ELEMS (B_N * OC * OD)   // 32768
#define IB 8                      // i's per block
#define ISTR (IC / IB)            // 256 i-stripes
#define BPB 32                    // b's per block (8 per wave)
#define BG (B_N / BPB)            // 2 b-groups

// async 16B global->LDS (direct, no VGPR round trip)
__device__ __forceinline__ void gll16(const float4* g, float4* l)
{
    __builtin_amdgcn_global_load_lds(
        (const __attribute__((address_space(1))) void*)g,
        (__attribute__((address_space(3))) void*)l,
        16, 0, 0);
}

// x + dpp_perm(x) on the VALU pipe (no LDS traffic)
template <int CTRL>
__device__ __forceinline__ float dpp_add(float x)
{
    union { float f; int i; } a, b;
    a.f = x;
    b.i = __builtin_amdgcn_update_dpp(0, a.i, CTRL, 0xF, 0xF, true);
    return x + b.f;
}

// W tile i is 1024 float4 "chunks"; global chunk f = (o*16 + j)*2 + dq.
// LDS layout: row o (32 chunks), chunk slot = (j*2+dq) ^ o.  Staging dest is
// linear D = s*256+tid; the matching pre-swizzled source is
//   f(D) = (D>>5)*32 + ((D&31) ^ (D>>5)).
// Hot read, fixed (jj,dq): lanes (o,jh) hit slot ((jh*16+jj*2+dq)^o) in row o
// -> slot%8 uniform over lanes -> conflict-free b128.

template <int FIRST>
__launch_bounds__(256, 2)
__global__ void caps_pass(const float* __restrict__ Wg,
                          const float* __restrict__ xg,
                          const float* __restrict__ vs,
                          __half* __restrict__ part)
{
    __shared__ float4 Wl[2][1024];      // 32 KB, double-buffered W tile
    __shared__ float4 xs[BPB * 2 * IB]; // 8 KB: x[b][i][h], all 8 i's, 32 b's

    const int tid  = threadIdx.x;
    const int lane = tid & 63;
    const int w    = tid >> 6;        // wave 0..3
    const int o    = lane & 31;
    const int jh   = lane >> 5;

    const int is   = blockIdx.x & (ISTR - 1);  // same-W blocks are 256 apart
    const int bg   = blockIdx.x >> 8;          // -> land on the same XCD
    const int bblk = bg * BPB;
    const int ig0  = is * IB;

    const float4* wq = (const float4*)Wg;
    const float4* xq = (const float4*)xg;

    // v-sum fragments for this wave's 8 b's, held across the i-loop
    float4 va[8], vb[8];
    if (!FIRST) {
#pragma unroll
        for (int n = 0; n < 8; ++n) {
            const float* vp =
                vs + (size_t)(bblk + w * 8 + n) * (OC * OD) + o * OD + jh * 8;
            va[n] = ((const float4*)vp)[0];
            vb[n] = ((const float4*)vp)[1];
        }
    }

    float acc[8][8];
#pragma unroll
    for (int n = 0; n < 8; ++n)
#pragma unroll
        for (int jj = 0; jj < 8; ++jj) acc[n][jj] = 0.0f;

    // stage W tile t into parity buffer (4 gll16 per thread)
    auto stage = [&](int t, int parity) {
        const size_t wb0 = (size_t)(ig0 + t) * 1024;
        float4* dst = Wl[parity];
#pragma unroll
        for (int s4 = 0; s4 < 4; ++s4) {
            const int D = s4 * 256 + tid;
            const int orow = D >> 5;
            const int f = orow * 32 + ((D & 31) ^ orow);
            gll16(wq + wb0 + f, dst + D);
        }
    };

    // ---- prologue: W tile 0 + ALL x for this (b-group, i-stripe).
    // xs slot s = b*16 + i*2 + h  <-  xq[((bblk+b)*IC + ig0)*2 + i*2+h]
    stage(0, 0);
#pragma unroll
    for (int q = 0; q < 2; ++q) {
        const int s  = q * 256 + tid;
        const int b  = s >> 4;
        const int rr = s & 15;
        gll16(xq + ((size_t)(bblk + b) * IC + ig0) * 2 + rr, &xs[s]);
    }

    for (int il = 0; il < IB; ++il) {
        const int p = il & 1;
        __syncthreads();   // tile il (and il=0: x) landed; parity p^1 free

        if (il + 1 < IB) stage(il + 1, p ^ 1);

        // W fragment -> registers (16 conflict-free ds_read_b128)
        float4 wA[8], wB[8];
        const int row = o * 32;
#pragma unroll
        for (int jj = 0; jj < 8; ++jj) {
            const int ca = (jh * 16 + jj * 2) ^ o;   // dq=0 slot
            wA[jj] = Wl[p][row + ca];
            wB[jj] = Wl[p][row + (ca ^ 1)];          // dq=1 slot
        }

#pragma unroll
        for (int n = 0; n < 8; ++n) {
            const float4 xa = xs[(w * 8 + n) * 16 + il * 2];
            const float4 xb = xs[(w * 8 + n) * 16 + il * 2 + 1];
            float u[8];
#pragma unroll
            for (int jj = 0; jj < 8; ++jj) {
                float t = wA[jj].x * xa.x;
                t = fmaf(wA[jj].y, xa.y, t);
                t = fmaf(wA[jj].z, xa.z, t);
                t = fmaf(wA[jj].w, xa.w, t);
                t = fmaf(wB[jj].x, xb.x, t);
                t = fmaf(wB[jj].y, xb.y, t);
                t = fmaf(wB[jj].z, xb.z, t);
                t = fmaf(wB[jj].w, xb.w, t);
                u[jj] = t;
            }
            float cc;
            if (FIRST) {
                cc = 1.0f;  // softmax(0) = 1/32, folded into the store scale
            } else {
                float bp = u[0] * va[n].x;
                bp = fmaf(u[1], va[n].y, bp);
                bp = fmaf(u[2], va[n].z, bp);
                bp = fmaf(u[3], va[n].w, bp);
                bp = fmaf(u[4], vb[n].x, bp);
                bp = fmaf(u[5], vb[n].y, bp);
                bp = fmaf(u[6], vb[n].z, bp);
                bp = fmaf(u[7], vb[n].w, bp);
                bp += __shfl_xor(bp, 32);            // combine j-halves
                // no max-subtraction: |logit| tiny, exp safe in fp32
                const float e = __expf(bp);
                float t = dpp_add<0xB1>(e);          // quad_perm xor1
                t = dpp_add<0x4E>(t);                // quad_perm xor2
                t = dpp_add<0x124>(t);               // row_ror:4
                t = dpp_add<0x128>(t);               // row_ror:8 -> row sum
                const float se = t + __shfl_xor(t, 16);  // 32-o total
                cc = e * __builtin_amdgcn_rcpf(se);
            }
#pragma unroll
            for (int jj = 0; jj < 8; ++jj)
                acc[n][jj] = fmaf(cc, u[jj], acc[n][jj]);
        }
    }

    // disjoint per-(istripe, b) fp16 partials — no atomics, no memset needed
    const float scale = FIRST ? (1.0f / 32.0f) : 1.0f;
#pragma unroll
    for (int n = 0; n < 8; ++n) {
        __half* dst = part + (size_t)is * S_ELEMS
                    + (size_t)(bblk + w * 8 + n) * (OC * OD) + o * OD + jh * 8;
        union { __half h[8]; uint4 u4; } pk;
#pragma unroll
        for (int jj = 0; jj < 8; ++jj)
            pk.h[jj] = __float2half(acc[n][jj] * scale);
        *(uint4*)dst = pk.u4;   // 16B-aligned: (o*16 + jh*8)*2 bytes
    }
}

// Fused 256-way fp16-partial reduction + squash, 512 blocks (2/CU).
// Block handles 64 elems; wave w sums stripes k===w (mod 4), coalesced 128B
// wave-loads; 4-way LDS combine; squash over 16-j lane groups.
// MODE 0: vsum = v   MODE 1: vsum += v   MODE 2: out = v
template <int MODE>
__launch_bounds__(256, 4)
__global__ void caps_reduce(const __half* __restrict__ part,
                            float* __restrict__ vsum,
                            float* __restrict__ out)
{
    __shared__ float red[4][64];
    const int tid  = threadIdx.x;
    const int w    = tid >> 6;
    const int lane = tid & 63;
    const int e0   = blockIdx.x * 64;

    float s = 0.0f;
#pragma unroll 8
    for (int k = w; k < ISTR; k += 4)
        s += __half2float(part[(size_t)k * S_ELEMS + e0 + lane]);
    red[w][lane] = s;
    __syncthreads();

    if (tid < 64) {
        const float t = red[0][tid] + red[1][tid] + red[2][tid] + red[3][tid];
        float s2 = t * t;               // ||s||^2 over the 16 j's
        s2 += __shfl_xor(s2, 1);
        s2 += __shfl_xor(s2, 2);
        s2 += __shfl_xor(s2, 4);
        s2 += __shfl_xor(s2, 8);
        const float v = t * (s2 / ((1.0f + s2) * sqrtf(s2 + 1e-9f)));
        const int e = e0 + tid;
        if (MODE == 0)      vsum[e] = v;
        else if (MODE == 1) vsum[e] += v;
        else                out[e] = v;
    }
}

extern "C" void kernel_launch(void* const* d_in, const int* in_sizes, int n_in,
                              void* d_out, int out_size, void* d_ws, size_t ws_size,
                              hipStream_t stream)
{
    const float* x = (const float*)d_in[0];   // [64, 2048, 8]
    const float* W = (const float*)d_in[1];   // [1, 2048, 32, 16, 8]
    float* out = (float*)d_out;               // [64, 32, 16]

    __half* part = (__half*)d_ws;             // 256 x 32768 x 2B = 16.8 MB
    float* vsum = (float*)((char*)d_ws + (size_t)ISTR * S_ELEMS * sizeof(__half));

    const dim3 gP(BG * ISTR);     // 512 blocks = 2/CU
    const dim3 bP(256);
    const dim3 gR(S_ELEMS / 64);  // 512 blocks
    const dim3 bR(256);

    // round 0: c uniform
    caps_pass<1><<<gP, bP, 0, stream>>>(W, x, nullptr, part);
    caps_reduce<0><<<gR, bR, 0, stream>>>(part, vsum, out);   // vsum = v0
    // round 1: b = u.v0
    caps_pass<0><<<gP, bP, 0, stream>>>(W, x, vsum, part);
    caps_reduce<1><<<gR, bR, 0, stream>>>(part, vsum, out);   // vsum = v0+v1
    // round 2: b = u.(v0+v1)
    caps_pass<0><<<gP, bP, 0, stream>>>(W, x, vsum, part);
    caps_reduce<2><<<gR, bR, 0, stream>>>(part, vsum, out);   // out = v2
}

// Round 12
// 165.116 us; speedup vs baseline: 3.2533x; 1.0102x over previous
//
#include <hip/hip_runtime.h>
#include <hip/hip_fp16.h>
#include <math.h>

// CapsuleLayer dynamic routing, fp32, MI355X (gfx950).
// B=64, IN_CAPS=2048, IN_DIM=8, OUT_CAPS=32, OUT_DIM=16, 3 routing iters.
//
// b_ij after r updates = u_hat_i . (v0+...+v_{r-1}) (b starts at 0), so no
// u_hat materialization: each pass recomputes u_hat from W via LDS staging.
//
// R13 -> R14: 8th structural null (167 -> 166.8). Fresh audit of the wave
// instruction stream: the softmax's two __shfl_xor (32, 16) compile to
// ds_permute/ds_swizzle = LDS OPS with ~120cyc latency, embedded as SERIAL
// links in each of the 8 per-n softmax chains. That adds 16 LDS ops per
// wave-iter (LDS pipe ~12.8us/pass -- the real co-binder) and ~240cyc of
// unhideable per-chain latency (why occupancy/pipelining probes were all
// null). R14 replaces both with gfx950 permlane swaps (VALU, no LDS):
//   r = permlane32_swap(x,x): r.x + r.y == x[lane] + x[lane^32]  (all lanes)
//   r = permlane16_swap(x,x): r.x + r.y == x[lane] + x[lane^16]  (all lanes)
// Softmax now has ZERO LDS ops; chain latency ~300 -> ~70cyc. The 8-term
// b-logit dot is tree-ified (depth 32 -> 16cyc). Everything else is
// byte-identical R13 (BPB=32, IB=8, gll16+XOR swizzle, one-shot x preload,
// fp16 partials, (256,2) no-pressure bounds).

#define IC 2048
#define ID 8
#define OC 32
#define OD 16
#define B_N 64
#define S_ELEMS (B_N * OC * OD)   // 32768
#define IB 8                      // i's per block
#define ISTR (IC / IB)            // 256 i-stripes
#define BPB 32                    // b's per block (8 per wave)
#define BG (B_N / BPB)            // 2 b-groups

// async 16B global->LDS (direct, no VGPR round trip)
__device__ __forceinline__ void gll16(const float4* g, float4* l)
{
    __builtin_amdgcn_global_load_lds(
        (const __attribute__((address_space(1))) void*)g,
        (__attribute__((address_space(3))) void*)l,
        16, 0, 0);
}

// x + dpp_perm(x) on the VALU pipe (no LDS traffic)
template <int CTRL>
__device__ __forceinline__ float dpp_add(float x)
{
    union { float f; int i; } a, b;
    a.f = x;
    b.i = __builtin_amdgcn_update_dpp(0, a.i, CTRL, 0xF, 0xF, true);
    return x + b.f;
}

typedef int v2i __attribute__((ext_vector_type(2)));

// x[lane] + x[lane^32] in every lane, pure VALU (v_permlane32_swap_b32)
__device__ __forceinline__ float swap32_sum(float x)
{
    union { float f; int i; } u; u.f = x;
    v2i r = __builtin_amdgcn_permlane32_swap(u.i, u.i, false, false);
    union { int i; float f; } a, b; a.i = r.x; b.i = r.y;
    return a.f + b.f;
}

// x[lane] + x[lane^16] in every lane, pure VALU (v_permlane16_swap_b32)
__device__ __forceinline__ float swap16_sum(float x)
{
    union { float f; int i; } u; u.f = x;
    v2i r = __builtin_amdgcn_permlane16_swap(u.i, u.i, false, false);
    union { int i; float f; } a, b; a.i = r.x; b.i = r.y;
    return a.f + b.f;
}

// W tile i is 1024 float4 "chunks"; global chunk f = (o*16 + j)*2 + dq.
// LDS layout: row o (32 chunks), chunk slot = (j*2+dq) ^ o.  Staging dest is
// linear D = s*256+tid; the matching pre-swizzled source is
//   f(D) = (D>>5)*32 + ((D&31) ^ (D>>5)).
// Hot read, fixed (jj,dq): lanes (o,jh) hit slot ((jh*16+jj*2+dq)^o) in row o
// -> slot%8 uniform over lanes -> conflict-free b128.

template <int FIRST>
__launch_bounds__(256, 2)
__global__ void caps_pass(const float* __restrict__ Wg,
                          const float* __restrict__ xg,
                          const float* __restrict__ vs,
                          __half* __restrict__ part)
{
    __shared__ float4 Wl[2][1024];      // 32 KB, double-buffered W tile
    __shared__ float4 xs[BPB * 2 * IB]; // 8 KB: x[b][i][h], all 8 i's, 32 b's

    const int tid  = threadIdx.x;
    const int lane = tid & 63;
    const int w    = tid >> 6;        // wave 0..3
    const int o    = lane & 31;
    const int jh   = lane >> 5;

    const int is   = blockIdx.x & (ISTR - 1);  // same-W blocks are 256 apart
    const int bg   = blockIdx.x >> 8;          // -> land on the same XCD
    const int bblk = bg * BPB;
    const int ig0  = is * IB;

    const float4* wq = (const float4*)Wg;
    const float4* xq = (const float4*)xg;

    // v-sum fragments for this wave's 8 b's, held across the i-loop
    float4 va[8], vb[8];
    if (!FIRST) {
#pragma unroll
        for (int n = 0; n < 8; ++n) {
            const float* vp =
                vs + (size_t)(bblk + w * 8 + n) * (OC * OD) + o * OD + jh * 8;
            va[n] = ((const float4*)vp)[0];
            vb[n] = ((const float4*)vp)[1];
        }
    }

    float acc[8][8];
#pragma unroll
    for (int n = 0; n < 8; ++n)
#pragma unroll
        for (int jj = 0; jj < 8; ++jj) acc[n][jj] = 0.0f;

    // stage W tile t into parity buffer (4 gll16 per thread)
    auto stage = [&](int t, int parity) {
        const size_t wb0 = (size_t)(ig0 + t) * 1024;
        float4* dst = Wl[parity];
#pragma unroll
        for (int s4 = 0; s4 < 4; ++s4) {
            const int D = s4 * 256 + tid;
            const int orow = D >> 5;
            const int f = orow * 32 + ((D & 31) ^ orow);
            gll16(wq + wb0 + f, dst + D);
        }
    };

    // ---- prologue: W tile 0 + ALL x for this (b-group, i-stripe).
    // xs slot s = b*16 + i*2 + h  <-  xq[((bblk+b)*IC + ig0)*2 + i*2+h]
    stage(0, 0);
#pragma unroll
    for (int q = 0; q < 2; ++q) {
        const int s  = q * 256 + tid;
        const int b  = s >> 4;
        const int rr = s & 15;
        gll16(xq + ((size_t)(bblk + b) * IC + ig0) * 2 + rr, &xs[s]);
    }

    for (int il = 0; il < IB; ++il) {
        const int p = il & 1;
        __syncthreads();   // tile il (and il=0: x) landed; parity p^1 free

        if (il + 1 < IB) stage(il + 1, p ^ 1);

        // W fragment -> registers (16 conflict-free ds_read_b128)
        float4 wA[8], wB[8];
        const int row = o * 32;
#pragma unroll
        for (int jj = 0; jj < 8; ++jj) {
            const int ca = (jh * 16 + jj * 2) ^ o;   // dq=0 slot
            wA[jj] = Wl[p][row + ca];
            wB[jj] = Wl[p][row + (ca ^ 1)];          // dq=1 slot
        }

#pragma unroll
        for (int n = 0; n < 8; ++n) {
            const float4 xa = xs[(w * 8 + n) * 16 + il * 2];
            const float4 xb = xs[(w * 8 + n) * 16 + il * 2 + 1];
            float u[8];
#pragma unroll
            for (int jj = 0; jj < 8; ++jj) {
                float t = wA[jj].x * xa.x;
                t = fmaf(wA[jj].y, xa.y, t);
                t = fmaf(wA[jj].z, xa.z, t);
                t = fmaf(wA[jj].w, xa.w, t);
                t = fmaf(wB[jj].x, xb.x, t);
                t = fmaf(wB[jj].y, xb.y, t);
                t = fmaf(wB[jj].z, xb.z, t);
                t = fmaf(wB[jj].w, xb.w, t);
                u[jj] = t;
            }
            float cc;
            if (FIRST) {
                cc = 1.0f;  // softmax(0) = 1/32, folded into the store scale
            } else {
                // tree-ified half-dot (depth ~16cyc)
                const float d0 = fmaf(u[1], va[n].y, u[0] * va[n].x);
                const float d1 = fmaf(u[3], va[n].w, u[2] * va[n].z);
                const float d2 = fmaf(u[5], vb[n].y, u[4] * vb[n].x);
                const float d3 = fmaf(u[7], vb[n].w, u[6] * vb[n].z);
                const float bph = (d0 + d1) + (d2 + d3);
                const float bp = swap32_sum(bph);    // combine j-halves (VALU)
                // no max-subtraction: |logit| tiny, exp safe in fp32
                const float e = __expf(bp);
                float t = dpp_add<0xB1>(e);          // quad_perm xor1
                t = dpp_add<0x4E>(t);                // quad_perm xor2
                t = dpp_add<0x124>(t);               // row_ror:4
                t = dpp_add<0x128>(t);               // row_ror:8 -> 16-row sum
                const float se = swap16_sum(t);      // 32-o total (VALU)
                cc = e * __builtin_amdgcn_rcpf(se);
            }
#pragma unroll
            for (int jj = 0; jj < 8; ++jj)
                acc[n][jj] = fmaf(cc, u[jj], acc[n][jj]);
        }
    }

    // disjoint per-(istripe, b) fp16 partials — no atomics, no memset needed
    const float scale = FIRST ? (1.0f / 32.0f) : 1.0f;
#pragma unroll
    for (int n = 0; n < 8; ++n) {
        __half* dst = part + (size_t)is * S_ELEMS
                    + (size_t)(bblk + w * 8 + n) * (OC * OD) + o * OD + jh * 8;
        union { __half h[8]; uint4 u4; } pk;
#pragma unroll
        for (int jj = 0; jj < 8; ++jj)
            pk.h[jj] = __float2half(acc[n][jj] * scale);
        *(uint4*)dst = pk.u4;   // 16B-aligned: (o*16 + jh*8)*2 bytes
    }
}

// Fused 256-way fp16-partial reduction + squash, 512 blocks (2/CU).
// Block handles 64 elems; wave w sums stripes k===w (mod 4), coalesced 128B
// wave-loads; 4-way LDS combine; squash over 16-j lane groups.
// MODE 0: vsum = v   MODE 1: vsum += v   MODE 2: out = v
template <int MODE>
__launch_bounds__(256, 4)
__global__ void caps_reduce(const __half* __restrict__ part,
                            float* __restrict__ vsum,
                            float* __restrict__ out)
{
    __shared__ float red[4][64];
    const int tid  = threadIdx.x;
    const int w    = tid >> 6;
    const int lane = tid & 63;
    const int e0   = blockIdx.x * 64;

    float s = 0.0f;
#pragma unroll 8
    for (int k = w; k < ISTR; k += 4)
        s += __half2float(part[(size_t)k * S_ELEMS + e0 + lane]);
    red[w][lane] = s;
    __syncthreads();

    if (tid < 64) {
        const float t = red[0][tid] + red[1][tid] + red[2][tid] + red[3][tid];
        float s2 = t * t;               // ||s||^2 over the 16 j's
        s2 += __shfl_xor(s2, 1);
        s2 += __shfl_xor(s2, 2);
        s2 += __shfl_xor(s2, 4);
        s2 += __shfl_xor(s2, 8);
        const float v = t * (s2 / ((1.0f + s2) * sqrtf(s2 + 1e-9f)));
        const int e = e0 + tid;
        if (MODE == 0)      vsum[e] = v;
        else if (MODE == 1) vsum[e] += v;
        else                out[e] = v;
    }
}

extern "C" void kernel_launch(void* const* d_in, const int* in_sizes, int n_in,
                              void* d_out, int out_size, void* d_ws, size_t ws_size,
                              hipStream_t stream)
{
    const float* x = (const float*)d_in[0];   // [64, 2048, 8]
    const float* W = (const float*)d_in[1];   // [1, 2048, 32, 16, 8]
    float* out = (float*)d_out;               // [64, 32, 16]

    __half* part = (__half*)d_ws;             // 256 x 32768 x 2B = 16.8 MB
    float* vsum = (float*)((char*)d_ws + (size_t)ISTR * S_ELEMS * sizeof(__half));

    const dim3 gP(BG * ISTR);     // 512 blocks = 2/CU
    const dim3 bP(256);
    const dim3 gR(S_ELEMS / 64);  // 512 blocks
    const dim3 bR(256);

    // round 0: c uniform
    caps_pass<1><<<gP, bP, 0, stream>>>(W, x, nullptr, part);
    caps_reduce<0><<<gR, bR, 0, stream>>>(part, vsum, out);   // vsum = v0
    // round 1: b = u.v0
    caps_pass<0><<<gP, bP, 0, stream>>>(W, x, vsum, part);
    caps_reduce<1><<<gR, bR, 0, stream>>>(part, vsum, out);   // vsum = v0+v1
    // round 2: b = u.(v0+v1)
    caps_pass<0><<<gP, bP, 0, stream>>>(W, x, vsum, part);
    caps_reduce<2><<<gR, bR, 0, stream>>>(part, vsum, out);   // out = v2
}